// Round 10
// baseline (92.683 us; speedup 1.0000x reference)
//
#include <hip/hip_runtime.h>
#include <math.h>

#define NS 256000
#define N1 512            // FFT over n1: radix 8,8,8
#define N2 500            // FFT over n2: radices 5,5,5,4
#define PI_F 3.14159265358979323846f

typedef float2 cplx;

__device__ __forceinline__ cplx cadd(cplx a, cplx b){ return make_float2(a.x+b.x, a.y+b.y); }
__device__ __forceinline__ cplx csub(cplx a, cplx b){ return make_float2(a.x-b.x, a.y-b.y); }
__device__ __forceinline__ cplx cmul(cplx a, cplx b){ return make_float2(a.x*b.x-a.y*b.y, a.x*b.y+a.y*b.x); }
__device__ __forceinline__ cplx cmulc(cplx a, cplx b){ return make_float2(a.x*b.x+a.y*b.y, a.y*b.x-a.x*b.y); }
__device__ __forceinline__ cplx crotf(cplx v, float ang){
    float sn = __sinf(ang), cs = __cosf(ang);
    return make_float2(v.x*cs - v.y*sn, v.x*sn + v.y*cs);
}
// padded LDS index: +1 word every 16 elements -> <=2-way bank aliasing
__device__ __forceinline__ int PX(int e){ return e + (e>>4); }
// octal digit reversal of 9 bits (involution)
__device__ __forceinline__ int rev8_3(int k){ return ((k&7)<<6) | (k&0x38) | (k>>6); }

#define U1PAD 545   // >= PX(511)+1 = 543
#define U2PAD 537   // >= PX(499)+1 = 531
// wave-level LDS fence: wave-private columns, no block barrier needed
#define WFENCE() asm volatile("s_waitcnt lgkmcnt(0)" ::: "memory")
// LDS-only block barrier: does NOT drain vmcnt, so global loads stay in flight
#define LDS_BARRIER() do{ asm volatile("s_waitcnt lgkmcnt(0)" ::: "memory"); __builtin_amdgcn_s_barrier(); }while(0)

template<bool INV>
__device__ __forceinline__ void dft4(const cplx* a, cplx* b){
    cplx t0=cadd(a[0],a[2]), t1=csub(a[0],a[2]), t2=cadd(a[1],a[3]), t3=csub(a[1],a[3]);
    b[0]=cadd(t0,t2); b[2]=csub(t0,t2);
    if(!INV){ b[1]=make_float2(t1.x+t3.y, t1.y-t3.x); b[3]=make_float2(t1.x-t3.y, t1.y+t3.x); }
    else    { b[1]=make_float2(t1.x-t3.y, t1.y+t3.x); b[3]=make_float2(t1.x+t3.y, t1.y-t3.x); }
}

template<bool INV>
__device__ __forceinline__ void dft8(const cplx* a, cplx* b){
    cplx ev[4]={a[0],a[2],a[4],a[6]}, od[4]={a[1],a[3],a[5],a[7]};
    cplx C[4], D[4];
    dft4<INV>(ev, C); dft4<INV>(od, D);
    const float s = 0.70710678118654752f;
    const float sg = INV ? 1.f : -1.f;
    cplx d1 = cmul(D[1], make_float2( s, sg*s));
    cplx d2 = cmul(D[2], make_float2(0.f, sg ));
    cplx d3 = cmul(D[3], make_float2(-s, sg*s));
    b[0]=cadd(C[0],D[0]); b[4]=csub(C[0],D[0]);
    b[1]=cadd(C[1],d1);   b[5]=csub(C[1],d1);
    b[2]=cadd(C[2],d2);   b[6]=csub(C[2],d2);
    b[3]=cadd(C[3],d3);   b[7]=csub(C[3],d3);
}

template<bool INV>
__device__ __forceinline__ void dft5(const cplx* a, cplx* b){
    const float c1=0.30901699437494742f, s1=0.95105651629515357f;
    const float c2=-0.80901699437494745f, s2=0.58778525229247312f;
    const float sg = INV ? 1.f : -1.f;
    cplx W[5];
    W[0]=make_float2(1.f,0.f);
    W[1]=make_float2(c1, sg*s1); W[2]=make_float2(c2, sg*s2);
    W[3]=make_float2(c2,-sg*s2); W[4]=make_float2(c1,-sg*s1);
#pragma unroll
    for(int u=0;u<5;++u){
        cplx acc = a[0];
        int idx = 0;
#pragma unroll
        for(int r=1;r<5;++r){
            idx += u; if(idx >= 5) idx -= 5;
            acc = cadd(acc, cmul(a[r], W[idx]));
        }
        b[u] = acc;
    }
}

// wave-private in-place stage: all reads issued first, then compute+write.
template<int R, int L, int TMUL, bool INV, int NN>
__device__ __forceinline__ void wstage(cplx* Uw, const cplx* tab, int lane){
    constexpr int m = L / R;
    constexpr int nb = NN / R;
    constexpr int NIT = (nb + 63) / 64;
    cplx a[NIT][R];
    cplx wt[NIT][R];   // wt[][0] unused
    int  bs[NIT];
#pragma unroll
    for(int it=0; it<NIT; ++it){
        int beta = lane + it*64;
        int blk = beta / m;
        int j = beta - blk*m;
        bs[it] = blk*L + j;
        if(beta < nb){
#pragma unroll
            for(int t=0;t<R;++t) a[it][t] = Uw[PX(bs[it] + m*t)];
#pragma unroll
            for(int t=1;t<R;++t) wt[it][t] = tab[TMUL*j*t];
        }
    }
#pragma unroll
    for(int it=0; it<NIT; ++it){
        int beta = lane + it*64;
        if(beta < nb){
            if(INV){
#pragma unroll
                for(int t=1;t<R;++t) a[it][t] = cmulc(a[it][t], wt[it][t]);
            }
            cplx bb[R];
            if constexpr (R==4) dft4<INV>(a[it], bb);
            else if constexpr (R==5) dft5<INV>(a[it], bb);
            else dft8<INV>(a[it], bb);
            if(!INV){
#pragma unroll
                for(int t=1;t<R;++t) bb[t] = cmul(bb[t], wt[it][t]);
            }
#pragma unroll
            for(int t=0;t<R;++t) Uw[PX(bs[it] + m*t)] = bb[t];
        }
    }
}

template<int NTAB, int NTHR>
__device__ __forceinline__ void build_tab(cplx* tab, int tid){
    const float step = -2.f*PI_F/(float)NTAB;
    for(int i = tid; i < NTAB; i += NTHR){
        float a = step*(float)i;
        tab[i] = make_float2(__cosf(a), __sinf(a));
    }
}

// position p -> true k2 for the radix-(5,5,5,4) DIF order
__device__ __forceinline__ int p2k2(int p){
    int t1 = p/100; int r = p - 100*t1;
    int t2 = r/20;  r -= 20*t2;
    int t3 = r>>2;  int t4 = r & 3;
    return t1 + 5*t2 + 25*t3 + 125*t4;
}
// true k2 -> position p (inverse of p2k2)
__device__ __forceinline__ int k22p(int k){
    int t1 = k % 5; int k5 = k/5;
    int t2 = k5 % 5; int k25 = k5/5;
    int t3 = k25 % 5; int t4 = k25/5;
    return 100*t1 + 20*t2 + 4*t3 + t4;
}
// slot -> true k1.  Conjugate pairs (k1, 512-k1) in adjacent slots:
// slot 0,1 = {0, 256} (self-paired), slot 2j,2j+1 = {j, 512-j} for j>=1.
__device__ __forceinline__ int colord(int q){
    int j = q>>1, w = q&1;
    if(j == 0) return w ? 256 : 0;
    return w ? 512 - j : j;
}
// bijective XCD-chunk swizzle
__device__ __forceinline__ int xcd_chunk(int bid, int n){
    int q = n>>3, r = n&7;
    int x = bid&7, idx = bid>>3;
    return (x < r ? x*(q+1) : r*(q+1) + (x-r)*q) + idx;
}

// packed conjugate-pair filter
__device__ __forceinline__ void hpair(cplx Z1, cplx Z2, float ha, float hb,
                                      cplx* zk, cplx* znk){
    float xr = 0.5f*(Z1.x + Z2.x), xi = 0.5f*(Z1.y - Z2.y);   // Xa
    float yr = 0.5f*(Z1.y + Z2.y), yi = -0.5f*(Z1.x - Z2.x);  // Xb
    *zk  = make_float2(ha*xr - hb*yi, ha*xi + hb*yr);
    *znk = make_float2(ha*xr + hb*yi, hb*yr - ha*xi);
}

// ---------------------------------------------------------------------------
// K1: blocks 0..3 = frame-mean weights (8-way ILP fm reduction); block 4 =
// logff; blocks 5.. = packed forward 512-FFT, 4 n2-columns per 4-wave block.
// ---------------------------------------------------------------------------
__global__ void __launch_bounds__(256) kFused1(const float* __restrict__ fm,
                                               const float* __restrict__ noise,
                                               float* __restrict__ mmL,
                                               cplx* __restrict__ Y){
    __shared__ float Aarr[500];
    __shared__ float wfr[500];
    __shared__ float part[256];
    __shared__ cplx tab[512];
    __shared__ cplx U[4][U1PAD];
    const int bid = blockIdx.x, tid = threadIdx.x;
    if(bid < 4){
        const int b = bid;
        for(int f = tid; f < 500; f += 256){
            long long i0 = ((long long)f*255999LL + 498LL)/499LL;
            long long i1 = ((long long)(f+1)*255999LL + 498LL)/499LL;
            long long cnt = i1 - i0;
            long long sumi = (i0 + i1 - 1)*cnt/2;
            long long num = 499LL*sumi - cnt*(long long)f*255999LL;
            Aarr[f] = (float)((double)num / 255999.0);
        }
        __syncthreads();
        for(int f = tid; f < 500; f += 256){
            long long i0 = ((long long)f*255999LL + 498LL)/499LL;
            long long i1 = ((long long)(f+1)*255999LL + 498LL)/499LL;
            double w;
            if(f < 499) w = (double)(i1 - i0) - (double)Aarr[f] + (f > 0 ? (double)Aarr[f-1] : 0.0);
            else        w = (double)Aarr[498] + 1.0;
            wfr[f] = (float)(w / (double)NS);
        }
        __syncthreads();
        // fm reduction with 8 independent accumulators -> 8 loads in flight
        const int k = tid & 63, seg = tid >> 6;
        const int f0 = seg*125;
        float ac[8];
#pragma unroll
        for(int u=0;u<8;++u) ac[u] = 0.f;
#pragma unroll 1
        for(int f = 0; f < 120; f += 8){
#pragma unroll
            for(int u=0;u<8;++u)
                ac[u] += wfr[f0+f+u] * fm[(b*500 + f0+f+u)*64 + k];
        }
#pragma unroll
        for(int u=0;u<5;++u)
            ac[u] += wfr[f0+120+u] * fm[(b*500 + f0+120+u)*64 + k];
        float acc = ((ac[0]+ac[1]) + (ac[2]+ac[3])) + ((ac[4]+ac[5]) + (ac[6]+ac[7]));
        part[seg*64 + k] = acc;
        __syncthreads();
        if(tid < 64) mmL[b*64 + tid] = part[tid] + part[64+tid] + part[128+tid] + part[192+tid];
        return;
    }
    if(bid == 4){
        if(tid < 64){
            float ff = __expf(2.99573227f + (float)tid*(6.31218815f/63.f));  // 20*551.25^(t/63)
            mmL[256 + tid] = __logf(ff + 1e-7f);
        }
        return;
    }
    // ---- packed forward 512-FFT: 4 columns per block ----
    const int g = xcd_chunk(bid - 5, 250);     // [0,250)
    const int s = g / 125;                     // signal
    const int n2base = (g - s*125) * 4;
    const int lane = tid & 63, w = tid >> 6;
    build_tab<512,256>(tab, tid);
    const float* xa = noise + (size_t)(2*s)*NS + n2base;
    const float* xb = noise + (size_t)(2*s+1)*NS + n2base;
#pragma unroll
    for(int k=0;k<8;++k){
        int i = tid + 256*k;                   // [0,2048)
        int n1 = i >> 2, ws = i & 3;
        U[ws][PX(n1)] = make_float2(xa[n1*500 + ws], xb[n1*500 + ws]);
    }
    __syncthreads();
    cplx* Uw = U[w];
    wstage<8,512, 1,false,512>(Uw, tab, lane); WFENCE();
    wstage<8, 64, 8,false,512>(Uw, tab, lane); WFENCE();
    wstage<8,  8,64,false,512>(Uw, tab, lane); WFENCE();
    const int n2 = n2base + w;
    cplx* yp = Y + ((size_t)s*500 + n2)*N1;
    const float tw = -2.f*PI_F/(float)NS;
#pragma unroll
    for(int t=0;t<8;++t){
        int q = lane + 64*t;
        int c = colord(q);
        cplx v = Uw[PX(rev8_3(c))];
        v = crotf(v, tw*(float)(n2*c));
        yp[q] = v;
    }
}

// ---------------------------------------------------------------------------
// K2: 512 blocks x 128 thr — 2 independent blocks per CU (the occupancy
// experiment: when one block stalls on a fence/barrier, the other issues).
// Each block owns ONE conjugate pair (2 columns); each wave one FULL 500-pt
// column (wave-private stages).  Fused filter response; conjugate unpack ->
// filter -> repack between fwd/inv FFTs.  In-place on Y.
// ---------------------------------------------------------------------------
__global__ void __launch_bounds__(128) kFused2(cplx* __restrict__ Y,
                                               const float* __restrict__ mmL){
    __shared__ cplx tab[500];
    __shared__ cplx U[2][U2PAD];
    __shared__ float Hr[2][500];      // row k1=blk (or k1=0 when special)
    __shared__ float HrX[2][500];     // row k1=256 (special block only)
    __shared__ float mmS[2][64];
    __shared__ float lgf[64];
    const int tid = threadIdx.x, lane = tid & 63, w = tid >> 6;
    const int L = xcd_chunk(blockIdx.x, 512);
    const int su = L >> 8;
    const int blk = L & 255;              // pair index; slots 2*blk, 2*blk+1
    const int s0 = 2*blk;
    const int special = (blk == 0);
    cplx* Ybase = Y + (size_t)su*500*512 + s0;
    // issue the 2-column loads FIRST; in flight through tab/Hr compute
    cplx rg[8];
#pragma unroll
    for(int k=0;k<8;++k){
        int e = tid + 128*k;              // [0,1024) -> 1000 used
        rg[k] = (e < 1000) ? Ybase[(e>>1)*512 + (e&1)] : make_float2(0.f,0.f);
    }
    build_tab<500,128>(tab, tid);
    if(tid < 128) mmS[tid>>6][tid&63] = mmL[2*su*64 + tid];
    if(tid < 64)  lgf[tid] = mmL[256 + tid];
    LDS_BARRIER();                        // LDS visible; vmem NOT drained
    // filter response rows: r0 -> k1=blk (0 when special); r1 -> 256 (special)
    const int nrows = special ? 2 : 1;
    const float invN = 1.f/(float)NS;
    for(int idx = tid; idx < nrows*500; idx += 128){
        int r = (idx >= 500) ? 1 : 0;
        int p = idx - 500*r;
        int k1 = special ? (r ? 256 : 0) : blk;
        int k2 = p2k2(p);
        int kf = k1 + 512*k2;
        int kk = min(kf, NS - kf);
        float lf = __logf((float)kk*(22050.f/(float)NS) + 1e-7f);
        float wsum = 0.f, a0 = 0.f, a1 = 0.f;
#pragma unroll
        for(int jb=0;jb<64;++jb){
            float d = lf - lgf[jb];
            float e2 = __expf(-2.f*d*d);
            wsum += e2; a0 += e2*mmS[0][jb]; a1 += e2*mmS[1][jb];
        }
        float inv = invN/(wsum + 1e-7f);
        if(r==0){ Hr[0][p]  = a0*inv; Hr[1][p]  = a1*inv; }
        else    { HrX[0][p] = a0*inv; HrX[1][p] = a1*inv; }
    }
    // park loads into LDS (compiler inserts the vmcnt waits here)
#pragma unroll
    for(int k=0;k<8;++k){
        int e = tid + 128*k;
        if(e < 1000) U[e&1][PX(e>>1)] = rg[k];
    }
    __syncthreads();
    cplx* Uw = U[w];
    wstage<5,500,  1,false,500>(Uw, tab, lane); WFENCE();
    wstage<5,100,  5,false,500>(Uw, tab, lane); WFENCE();
    wstage<5, 20, 25,false,500>(Uw, tab, lane); WFENCE();
    wstage<4,  4,125,false,500>(Uw, tab, lane);
    __syncthreads();
    // ---- conjugate-pair unpack -> filter -> repack ----
    if(special){
        if(w == 0){
            // column k1=0, self-paired: partner k2' = (500-k2)%500
#pragma unroll 1
            for(int t=0;t<8;++t){
                int p = lane + 64*t;
                if(p < 500){
                    int k2 = p2k2(p);
                    int pp = k22p((500 - k2) % 500);
                    if(p <= pp){
                        cplx Z1 = U[0][PX(p)], Z2 = U[0][PX(pp)];
                        cplx zk, znk;
                        hpair(Z1, Z2, Hr[0][p], Hr[1][p], &zk, &znk);
                        U[0][PX(p)]  = zk;
                        U[0][PX(pp)] = znk;
                    }
                }
            }
        } else {
            // column k1=256, self-paired: partner position 499-p
#pragma unroll 1
            for(int t=0;t<4;++t){
                int p = lane + 64*t;
                if(p < 250){
                    cplx Z1 = U[1][PX(p)], Z2 = U[1][PX(499-p)];
                    cplx zk, znk;
                    hpair(Z1, Z2, HrX[0][p], HrX[1][p], &zk, &znk);
                    U[1][PX(p)]     = zk;
                    U[1][PX(499-p)] = znk;
                }
            }
        }
    } else {
        // cross pair: (col blk, p) <-> (col 512-blk, 499-p); wave w owns
        // p in [w*250, w*250+250) -> each wave reads/writes its own elements.
#pragma unroll 1
        for(int t=0;t<4;++t){
            int pl = lane + 64*t;
            if(pl < 250){
                int p = w*250 + pl;
                cplx Z1 = U[0][PX(p)], Z2 = U[1][PX(499-p)];
                cplx zk, znk;
                hpair(Z1, Z2, Hr[0][p], Hr[1][p], &zk, &znk);
                U[0][PX(p)]     = zk;
                U[1][PX(499-p)] = znk;
            }
        }
    }
    __syncthreads();
    wstage<4,  4,125,true,500>(Uw, tab, lane); WFENCE();
    wstage<5, 20, 25,true,500>(Uw, tab, lane); WFENCE();
    wstage<5,100,  5,true,500>(Uw, tab, lane); WFENCE();
    wstage<5,500,  1,true,500>(Uw, tab, lane);
    __syncthreads();                      // store reads across both columns
    const float tw2 = 2.f*PI_F/(float)NS;
#pragma unroll
    for(int k=0;k<8;++k){
        int e = tid + 128*k;
        if(e < 1000){
            int n2 = e >> 1, sl = e & 1;
            int cc = colord(s0 + sl);
            cplx v = U[sl][PX(n2)];
            v = crotf(v, tw2*(float)(n2*cc));
            Ybase[n2*512 + sl] = v;
        }
    }
}

// ---------------------------------------------------------------------------
// K3: inverse 512-FFT; 4 n2-columns per 4-wave block (wave-per-column).
// Re -> batch 2s, Im -> batch 2s+1.  grid = 250.
// ---------------------------------------------------------------------------
__global__ void __launch_bounds__(256) kFused3(const cplx* __restrict__ Y,
                                               float* __restrict__ out){
    __shared__ cplx tab[512];
    __shared__ cplx U[4][U1PAD];
    const int tid = threadIdx.x, lane = tid & 63, w = tid >> 6;
    const int g = xcd_chunk(blockIdx.x, 250);
    const int s = g / 125;
    const int n2base = (g - s*125) * 4;
    build_tab<512,256>(tab, tid);
    const cplx* yp = Y + ((size_t)s*500 + n2base)*N1;
#pragma unroll
    for(int k=0;k<8;++k){
        int i = tid + 256*k;                   // [0,2048)
        int ws = i >> 9, q = i & 511;          // coalesced in q
        cplx v = yp[(size_t)ws*N1 + q];
        U[ws][PX(rev8_3(colord(q)))] = v;      // bin c -> DIT position rev8_3(c)
    }
    __syncthreads();
    cplx* Uw = U[w];
    wstage<8,  8,64,true,512>(Uw, tab, lane); WFENCE();
    wstage<8, 64, 8,true,512>(Uw, tab, lane); WFENCE();
    wstage<8,512, 1,true,512>(Uw, tab, lane);
    __syncthreads();                           // store reads across columns
    float* oa = out + (size_t)(2*s)*NS + n2base;
    float* ob = out + (size_t)(2*s+1)*NS + n2base;
#pragma unroll
    for(int k=0;k<8;++k){
        int i = tid + 256*k;
        int n1 = i >> 2, ws = i & 3;
        cplx v = U[ws][PX(n1)];
        oa[n1*500 + ws] = v.x;
        ob[n1*500 + ws] = v.y;
    }
}

// ---------------------------------------------------------------------------
extern "C" void kernel_launch(void* const* d_in, const int* in_sizes, int n_in,
                              void* d_out, int out_size, void* d_ws, size_t ws_size,
                              hipStream_t stream) {
    const float* fm = (const float*)d_in[0];     // (4,500,64)
    const float* noise = (const float*)d_in[1];  // (4,256000)
    float* out = (float*)d_out;

    char* ws = (char*)d_ws;
    cplx*  Y   = (cplx*)ws;                      // 2 signals * 500 * 512 cplx = 4,096,000 B
    float* mmL = (float*)(ws + 4194304);         // mm[4][64] + logff[64]

    kFused1<<<255, 256, 0, stream>>>(fm, noise, mmL, Y);
    kFused2<<<512, 128, 0, stream>>>(Y, mmL);
    kFused3<<<250, 256, 0, stream>>>(Y, out);
}

// Round 11
// 89.055 us; speedup vs baseline: 1.0407x; 1.0407x over previous
//
#include <hip/hip_runtime.h>
#include <math.h>

#define NS 256000
#define N1 512            // FFT over n1: radix 8,8,8
#define N2 500            // FFT over n2: radices 5,5,5,4
#define PI_F 3.14159265358979323846f

typedef float2 cplx;

__device__ __forceinline__ cplx cadd(cplx a, cplx b){ return make_float2(a.x+b.x, a.y+b.y); }
__device__ __forceinline__ cplx csub(cplx a, cplx b){ return make_float2(a.x-b.x, a.y-b.y); }
__device__ __forceinline__ cplx cmul(cplx a, cplx b){ return make_float2(a.x*b.x-a.y*b.y, a.x*b.y+a.y*b.x); }
__device__ __forceinline__ cplx cmulc(cplx a, cplx b){ return make_float2(a.x*b.x+a.y*b.y, a.y*b.x-a.x*b.y); }
__device__ __forceinline__ cplx crotf(cplx v, float ang){
    float sn = __sinf(ang), cs = __cosf(ang);
    return make_float2(v.x*cs - v.y*sn, v.x*sn + v.y*cs);
}
// padded LDS index: +1 word every 16 elements -> <=2-way bank aliasing
__device__ __forceinline__ int PX(int e){ return e + (e>>4); }
// octal digit reversal of 9 bits (involution)
__device__ __forceinline__ int rev8_3(int k){ return ((k&7)<<6) | (k&0x38) | (k>>6); }

#define U1PAD 545   // >= PX(511)+1 = 543
#define U2PAD 537   // >= PX(499)+1 = 531
// wave-level LDS fence: wave-private columns, no block barrier needed
#define WFENCE() asm volatile("s_waitcnt lgkmcnt(0)" ::: "memory")
// LDS-only block barrier: does NOT drain vmcnt, so global loads stay in flight
#define LDS_BARRIER() do{ asm volatile("s_waitcnt lgkmcnt(0)" ::: "memory"); __builtin_amdgcn_s_barrier(); }while(0)

template<bool INV>
__device__ __forceinline__ void dft4(const cplx* a, cplx* b){
    cplx t0=cadd(a[0],a[2]), t1=csub(a[0],a[2]), t2=cadd(a[1],a[3]), t3=csub(a[1],a[3]);
    b[0]=cadd(t0,t2); b[2]=csub(t0,t2);
    if(!INV){ b[1]=make_float2(t1.x+t3.y, t1.y-t3.x); b[3]=make_float2(t1.x-t3.y, t1.y+t3.x); }
    else    { b[1]=make_float2(t1.x-t3.y, t1.y+t3.x); b[3]=make_float2(t1.x+t3.y, t1.y-t3.x); }
}

template<bool INV>
__device__ __forceinline__ void dft8(const cplx* a, cplx* b){
    cplx ev[4]={a[0],a[2],a[4],a[6]}, od[4]={a[1],a[3],a[5],a[7]};
    cplx C[4], D[4];
    dft4<INV>(ev, C); dft4<INV>(od, D);
    const float s = 0.70710678118654752f;
    const float sg = INV ? 1.f : -1.f;
    cplx d1 = cmul(D[1], make_float2( s, sg*s));
    cplx d2 = cmul(D[2], make_float2(0.f, sg ));
    cplx d3 = cmul(D[3], make_float2(-s, sg*s));
    b[0]=cadd(C[0],D[0]); b[4]=csub(C[0],D[0]);
    b[1]=cadd(C[1],d1);   b[5]=csub(C[1],d1);
    b[2]=cadd(C[2],d2);   b[6]=csub(C[2],d2);
    b[3]=cadd(C[3],d3);   b[7]=csub(C[3],d3);
}

template<bool INV>
__device__ __forceinline__ void dft5(const cplx* a, cplx* b){
    const float c1=0.30901699437494742f, s1=0.95105651629515357f;
    const float c2=-0.80901699437494745f, s2=0.58778525229247312f;
    const float sg = INV ? 1.f : -1.f;
    cplx W[5];
    W[0]=make_float2(1.f,0.f);
    W[1]=make_float2(c1, sg*s1); W[2]=make_float2(c2, sg*s2);
    W[3]=make_float2(c2,-sg*s2); W[4]=make_float2(c1,-sg*s1);
#pragma unroll
    for(int u=0;u<5;++u){
        cplx acc = a[0];
        int idx = 0;
#pragma unroll
        for(int r=1;r<5;++r){
            idx += u; if(idx >= 5) idx -= 5;
            acc = cadd(acc, cmul(a[r], W[idx]));
        }
        b[u] = acc;
    }
}

// wave-private in-place stage: all reads issued first, then compute+write.
template<int R, int L, int TMUL, bool INV, int NN>
__device__ __forceinline__ void wstage(cplx* Uw, const cplx* tab, int lane){
    constexpr int m = L / R;
    constexpr int nb = NN / R;
    constexpr int NIT = (nb + 63) / 64;
    cplx a[NIT][R];
    cplx wt[NIT][R];   // wt[][0] unused
    int  bs[NIT];
#pragma unroll
    for(int it=0; it<NIT; ++it){
        int beta = lane + it*64;
        int blk = beta / m;
        int j = beta - blk*m;
        bs[it] = blk*L + j;
        if(beta < nb){
#pragma unroll
            for(int t=0;t<R;++t) a[it][t] = Uw[PX(bs[it] + m*t)];
#pragma unroll
            for(int t=1;t<R;++t) wt[it][t] = tab[TMUL*j*t];
        }
    }
#pragma unroll
    for(int it=0; it<NIT; ++it){
        int beta = lane + it*64;
        if(beta < nb){
            if(INV){
#pragma unroll
                for(int t=1;t<R;++t) a[it][t] = cmulc(a[it][t], wt[it][t]);
            }
            cplx bb[R];
            if constexpr (R==4) dft4<INV>(a[it], bb);
            else if constexpr (R==5) dft5<INV>(a[it], bb);
            else dft8<INV>(a[it], bb);
            if(!INV){
#pragma unroll
                for(int t=1;t<R;++t) bb[t] = cmul(bb[t], wt[it][t]);
            }
#pragma unroll
            for(int t=0;t<R;++t) Uw[PX(bs[it] + m*t)] = bb[t];
        }
    }
}

template<int NTAB, int NTHR>
__device__ __forceinline__ void build_tab(cplx* tab, int tid){
    const float step = -2.f*PI_F/(float)NTAB;
    for(int i = tid; i < NTAB; i += NTHR){
        float a = step*(float)i;
        tab[i] = make_float2(__cosf(a), __sinf(a));
    }
}

// position p -> true k2 for the radix-(5,5,5,4) DIF order
__device__ __forceinline__ int p2k2(int p){
    int t1 = p/100; int r = p - 100*t1;
    int t2 = r/20;  r -= 20*t2;
    int t3 = r>>2;  int t4 = r & 3;
    return t1 + 5*t2 + 25*t3 + 125*t4;
}
// true k2 -> position p (inverse of p2k2)
__device__ __forceinline__ int k22p(int k){
    int t1 = k % 5; int k5 = k/5;
    int t2 = k5 % 5; int k25 = k5/5;
    int t3 = k25 % 5; int t4 = k25/5;
    return 100*t1 + 20*t2 + 4*t3 + t4;
}
// slot -> true k1.  Conjugate pairs (k1, 512-k1) in adjacent slots:
// slot 0,1 = {0, 256} (self-paired), slot 2j,2j+1 = {j, 512-j} for j>=1.
__device__ __forceinline__ int colord(int q){
    int j = q>>1, w = q&1;
    if(j == 0) return w ? 256 : 0;
    return w ? 512 - j : j;
}
// bijective XCD-chunk swizzle
__device__ __forceinline__ int xcd_chunk(int bid, int n){
    int q = n>>3, r = n&7;
    int x = bid&7, idx = bid>>3;
    return (x < r ? x*(q+1) : r*(q+1) + (x-r)*q) + idx;
}

// packed conjugate-pair filter
__device__ __forceinline__ void hpair(cplx Z1, cplx Z2, float ha, float hb,
                                      cplx* zk, cplx* znk){
    float xr = 0.5f*(Z1.x + Z2.x), xi = 0.5f*(Z1.y - Z2.y);   // Xa
    float yr = 0.5f*(Z1.y + Z2.y), yi = -0.5f*(Z1.x - Z2.x);  // Xb
    *zk  = make_float2(ha*xr - hb*yi, ha*xi + hb*yr);
    *znk = make_float2(ha*xr + hb*yi, hb*yr - ha*xi);
}

// ---------------------------------------------------------------------------
// K1: blocks 0..3 = frame-mean weights (8-way ILP fm reduction); block 4 =
// logff; blocks 5.. = packed forward 512-FFT, 4 n2-columns per 4-wave block.
// Noise loads vectorized: the block's 4 columns are 4 consecutive floats at
// each n1 -> one float4 per signal per n1.
// ---------------------------------------------------------------------------
__global__ void __launch_bounds__(256) kFused1(const float* __restrict__ fm,
                                               const float* __restrict__ noise,
                                               float* __restrict__ mmL,
                                               cplx* __restrict__ Y){
    __shared__ float Aarr[500];
    __shared__ float wfr[500];
    __shared__ float part[256];
    __shared__ cplx tab[512];
    __shared__ cplx U[4][U1PAD];
    const int bid = blockIdx.x, tid = threadIdx.x;
    if(bid < 4){
        const int b = bid;
        for(int f = tid; f < 500; f += 256){
            long long i0 = ((long long)f*255999LL + 498LL)/499LL;
            long long i1 = ((long long)(f+1)*255999LL + 498LL)/499LL;
            long long cnt = i1 - i0;
            long long sumi = (i0 + i1 - 1)*cnt/2;
            long long num = 499LL*sumi - cnt*(long long)f*255999LL;
            Aarr[f] = (float)((double)num / 255999.0);
        }
        __syncthreads();
        for(int f = tid; f < 500; f += 256){
            long long i0 = ((long long)f*255999LL + 498LL)/499LL;
            long long i1 = ((long long)(f+1)*255999LL + 498LL)/499LL;
            double w;
            if(f < 499) w = (double)(i1 - i0) - (double)Aarr[f] + (f > 0 ? (double)Aarr[f-1] : 0.0);
            else        w = (double)Aarr[498] + 1.0;
            wfr[f] = (float)(w / (double)NS);
        }
        __syncthreads();
        // fm reduction with 8 independent accumulators -> 8 loads in flight
        const int k = tid & 63, seg = tid >> 6;
        const int f0 = seg*125;
        float ac[8];
#pragma unroll
        for(int u=0;u<8;++u) ac[u] = 0.f;
#pragma unroll 1
        for(int f = 0; f < 120; f += 8){
#pragma unroll
            for(int u=0;u<8;++u)
                ac[u] += wfr[f0+f+u] * fm[(b*500 + f0+f+u)*64 + k];
        }
#pragma unroll
        for(int u=0;u<5;++u)
            ac[u] += wfr[f0+120+u] * fm[(b*500 + f0+120+u)*64 + k];
        float acc = ((ac[0]+ac[1]) + (ac[2]+ac[3])) + ((ac[4]+ac[5]) + (ac[6]+ac[7]));
        part[seg*64 + k] = acc;
        __syncthreads();
        if(tid < 64) mmL[b*64 + tid] = part[tid] + part[64+tid] + part[128+tid] + part[192+tid];
        return;
    }
    if(bid == 4){
        if(tid < 64){
            float ff = __expf(2.99573227f + (float)tid*(6.31218815f/63.f));  // 20*551.25^(t/63)
            mmL[256 + tid] = __logf(ff + 1e-7f);
        }
        return;
    }
    // ---- packed forward 512-FFT: 4 columns per block ----
    const int g = xcd_chunk(bid - 5, 250);     // [0,250)
    const int s = g / 125;                     // signal
    const int n2base = (g - s*125) * 4;
    const int lane = tid & 63, w = tid >> 6;
    build_tab<512,256>(tab, tid);
    const float* xa = noise + (size_t)(2*s)*NS + n2base;
    const float* xb = noise + (size_t)(2*s+1)*NS + n2base;
    // vectorized: one float4 per signal per n1 covers all 4 columns (16B, aligned)
#pragma unroll
    for(int k=0;k<2;++k){
        int n1 = tid + 256*k;                  // [0,512)
        float4 va = *(const float4*)(xa + n1*500);
        float4 vb = *(const float4*)(xb + n1*500);
        U[0][PX(n1)] = make_float2(va.x, vb.x);
        U[1][PX(n1)] = make_float2(va.y, vb.y);
        U[2][PX(n1)] = make_float2(va.z, vb.z);
        U[3][PX(n1)] = make_float2(va.w, vb.w);
    }
    __syncthreads();
    cplx* Uw = U[w];
    wstage<8,512, 1,false,512>(Uw, tab, lane); WFENCE();
    wstage<8, 64, 8,false,512>(Uw, tab, lane); WFENCE();
    wstage<8,  8,64,false,512>(Uw, tab, lane); WFENCE();
    const int n2 = n2base + w;
    cplx* yp = Y + ((size_t)s*500 + n2)*N1;
    const float tw = -2.f*PI_F/(float)NS;
#pragma unroll
    for(int t=0;t<8;++t){
        int q = lane + 64*t;
        int c = colord(q);
        cplx v = Uw[PX(rev8_3(c))];
        v = crotf(v, tw*(float)(n2*c));
        yp[q] = v;
    }
}

// ---------------------------------------------------------------------------
// K2: 256 blocks x 256 thr — ONE block-round on 256 CUs.  Each block owns 2
// conjugate pairs (4 columns = 32B contiguous per Y row); each wave owns one
// FULL 500-pt column (wave-private stages).  Fused filter response; conjugate
// unpack -> filter -> repack between fwd/inv FFTs.  In-place on Y.
// Y row I/O vectorized as 2x float4 per row.
// ---------------------------------------------------------------------------
__global__ void __launch_bounds__(256) kFused2(cplx* __restrict__ Y,
                                               const float* __restrict__ mmL){
    __shared__ cplx tab[500];
    __shared__ cplx U[4][U2PAD];
    __shared__ float Hr[2][2][500];   // [pair-unit][a0/a1][p]
    __shared__ float HrX[2][500];     // k1=256 rows (special block only)
    __shared__ float mmS[2][64];
    __shared__ float lgf[64];
    const int tid = threadIdx.x, lane = tid & 63, w = tid >> 6;
    const int L = xcd_chunk(blockIdx.x, 256);
    const int su = L >> 7;
    const int j0 = 2*(L & 127);           // first pair index (even)
    const int s0 = 2*j0;                  // first slot in Y (multiple of 4)
    cplx* Ybase = Y + (size_t)su*500*512 + s0;
    // issue the 4-column row loads FIRST (2x float4 per row, 32B aligned);
    // they stay in flight through tab/Hr compute
    float4 rA[2], rB[2];
#pragma unroll
    for(int k=0;k<2;++k){
        int r = tid + 256*k;              // [0,512) -> 500 used
        const float4* src = (const float4*)(Ybase + (size_t)r*512);
        if(r < 500){ rA[k] = src[0]; rB[k] = src[1]; }
        else       { rA[k] = make_float4(0,0,0,0); rB[k] = rA[k]; }
    }
    build_tab<500,256>(tab, tid);
    if(tid < 128) mmS[tid>>6][tid&63] = mmL[2*su*64 + tid];
    if(tid < 64)  lgf[tid] = mmL[256 + tid];
    LDS_BARRIER();                        // LDS visible; vmem NOT drained
    // filter response rows: r0 -> k1=j0, r1 -> j0+1, r2 -> 256 (special)
    const int special = (j0 == 0);
    const int nrows = special ? 3 : 2;
    const float invN = 1.f/(float)NS;
    for(int idx = tid; idx < nrows*500; idx += 256){
        int r = idx / 500;
        int p = idx - 500*r;
        int k1 = (r==0) ? j0 : ((r==1) ? j0+1 : 256);
        int k2 = p2k2(p);
        int kf = k1 + 512*k2;
        int kk = min(kf, NS - kf);
        float lf = __logf((float)kk*(22050.f/(float)NS) + 1e-7f);
        float wsum = 0.f, a0 = 0.f, a1 = 0.f;
#pragma unroll
        for(int jb=0;jb<64;++jb){
            float d = lf - lgf[jb];
            float e2 = __expf(-2.f*d*d);
            wsum += e2; a0 += e2*mmS[0][jb]; a1 += e2*mmS[1][jb];
        }
        float inv = invN/(wsum + 1e-7f);
        if(r < 2){ Hr[r][0][p] = a0*inv; Hr[r][1][p] = a1*inv; }
        else     { HrX[0][p]   = a0*inv; HrX[1][p]   = a1*inv; }
    }
    // park loads into LDS (compiler inserts the vmcnt waits here)
#pragma unroll
    for(int k=0;k<2;++k){
        int r = tid + 256*k;
        if(r < 500){
            U[0][PX(r)] = make_float2(rA[k].x, rA[k].y);
            U[1][PX(r)] = make_float2(rA[k].z, rA[k].w);
            U[2][PX(r)] = make_float2(rB[k].x, rB[k].y);
            U[3][PX(r)] = make_float2(rB[k].z, rB[k].w);
        }
    }
    __syncthreads();
    cplx* Uw = U[w];
    wstage<5,500,  1,false,500>(Uw, tab, lane); WFENCE();
    wstage<5,100,  5,false,500>(Uw, tab, lane); WFENCE();
    wstage<5, 20, 25,false,500>(Uw, tab, lane); WFENCE();
    wstage<4,  4,125,false,500>(Uw, tab, lane);
    __syncthreads();
    // ---- conjugate-pair unpack -> filter -> repack ----
    {
        const int u = w >> 1, cw = w & 1;
        cplx* UA = U[2*u];
        cplx* UB = U[2*u + 1];
        if(special && u == 0){
            if(cw == 0){
                // column k1=0, self-paired: partner k2' = (500-k2)%500
#pragma unroll 1
                for(int t=0;t<8;++t){
                    int p = lane + 64*t;
                    if(p < 500){
                        int k2 = p2k2(p);
                        int pp = k22p((500 - k2) % 500);
                        if(p <= pp){
                            cplx Z1 = UA[PX(p)], Z2 = UA[PX(pp)];
                            cplx zk, znk;
                            hpair(Z1, Z2, Hr[0][0][p], Hr[0][1][p], &zk, &znk);
                            UA[PX(p)]  = zk;
                            UA[PX(pp)] = znk;
                        }
                    }
                }
            } else {
                // column k1=256, self-paired: partner position 499-p
#pragma unroll 1
                for(int t=0;t<4;++t){
                    int p = lane + 64*t;
                    if(p < 250){
                        cplx Z1 = UB[PX(p)], Z2 = UB[PX(499-p)];
                        cplx zk, znk;
                        hpair(Z1, Z2, HrX[0][p], HrX[1][p], &zk, &znk);
                        UB[PX(p)]     = zk;
                        UB[PX(499-p)] = znk;
                    }
                }
            }
        } else {
            // cross pair j=j0+u: (col k1=j, p) <-> (col 512-j, 499-p);
            // wave cw owns p in [cw*250, cw*250+250) -> disjoint writes.
            const float* H0 = Hr[u][0];
            const float* H1 = Hr[u][1];
#pragma unroll 1
            for(int t=0;t<4;++t){
                int pl = lane + 64*t;
                if(pl < 250){
                    int p = cw*250 + pl;
                    cplx Z1 = UA[PX(p)], Z2 = UB[PX(499-p)];
                    cplx zk, znk;
                    hpair(Z1, Z2, H0[p], H1[p], &zk, &znk);
                    UA[PX(p)]     = zk;
                    UB[PX(499-p)] = znk;
                }
            }
        }
    }
    __syncthreads();
    wstage<4,  4,125,true,500>(Uw, tab, lane); WFENCE();
    wstage<5, 20, 25,true,500>(Uw, tab, lane); WFENCE();
    wstage<5,100,  5,true,500>(Uw, tab, lane); WFENCE();
    wstage<5,500,  1,true,500>(Uw, tab, lane);
    __syncthreads();                      // store reads across all 4 columns
    const float tw2 = 2.f*PI_F/(float)NS;
    const int c0 = colord(s0+0), c1 = colord(s0+1);
    const int c2 = colord(s0+2), c3 = colord(s0+3);
#pragma unroll
    for(int k=0;k<2;++k){
        int r = tid + 256*k;
        if(r < 500){
            cplx v0 = crotf(U[0][PX(r)], tw2*(float)(r*c0));
            cplx v1 = crotf(U[1][PX(r)], tw2*(float)(r*c1));
            cplx v2 = crotf(U[2][PX(r)], tw2*(float)(r*c2));
            cplx v3 = crotf(U[3][PX(r)], tw2*(float)(r*c3));
            float4* dst = (float4*)(Ybase + (size_t)r*512);
            dst[0] = make_float4(v0.x, v0.y, v1.x, v1.y);
            dst[1] = make_float4(v2.x, v2.y, v3.x, v3.y);
        }
    }
}

// ---------------------------------------------------------------------------
// K3: inverse 512-FFT; 4 n2-columns per 4-wave block (wave-per-column).
// Re -> batch 2s, Im -> batch 2s+1.  grid = 250.  Output stores vectorized:
// the 4 columns are 4 consecutive floats at each n1 -> float4 per signal.
// ---------------------------------------------------------------------------
__global__ void __launch_bounds__(256) kFused3(const cplx* __restrict__ Y,
                                               float* __restrict__ out){
    __shared__ cplx tab[512];
    __shared__ cplx U[4][U1PAD];
    const int tid = threadIdx.x, lane = tid & 63, w = tid >> 6;
    const int g = xcd_chunk(blockIdx.x, 250);
    const int s = g / 125;
    const int n2base = (g - s*125) * 4;
    build_tab<512,256>(tab, tid);
    const cplx* yp = Y + ((size_t)s*500 + n2base)*N1;
#pragma unroll
    for(int k=0;k<8;++k){
        int i = tid + 256*k;                   // [0,2048)
        int ws = i >> 9, q = i & 511;          // coalesced in q
        cplx v = yp[(size_t)ws*N1 + q];
        U[ws][PX(rev8_3(colord(q)))] = v;      // bin c -> DIT position rev8_3(c)
    }
    __syncthreads();
    cplx* Uw = U[w];
    wstage<8,  8,64,true,512>(Uw, tab, lane); WFENCE();
    wstage<8, 64, 8,true,512>(Uw, tab, lane); WFENCE();
    wstage<8,512, 1,true,512>(Uw, tab, lane);
    __syncthreads();                           // store reads across columns
    float* oa = out + (size_t)(2*s)*NS + n2base;
    float* ob = out + (size_t)(2*s+1)*NS + n2base;
#pragma unroll
    for(int k=0;k<2;++k){
        int n1 = tid + 256*k;                  // [0,512)
        cplx v0 = U[0][PX(n1)], v1 = U[1][PX(n1)];
        cplx v2 = U[2][PX(n1)], v3 = U[3][PX(n1)];
        *(float4*)(oa + n1*500) = make_float4(v0.x, v1.x, v2.x, v3.x);
        *(float4*)(ob + n1*500) = make_float4(v0.y, v1.y, v2.y, v3.y);
    }
}

// ---------------------------------------------------------------------------
extern "C" void kernel_launch(void* const* d_in, const int* in_sizes, int n_in,
                              void* d_out, int out_size, void* d_ws, size_t ws_size,
                              hipStream_t stream) {
    const float* fm = (const float*)d_in[0];     // (4,500,64)
    const float* noise = (const float*)d_in[1];  // (4,256000)
    float* out = (float*)d_out;

    char* ws = (char*)d_ws;
    cplx*  Y   = (cplx*)ws;                      // 2 signals * 500 * 512 cplx = 4,096,000 B
    float* mmL = (float*)(ws + 4194304);         // mm[4][64] + logff[64]

    kFused1<<<255, 256, 0, stream>>>(fm, noise, mmL, Y);
    kFused2<<<256, 256, 0, stream>>>(Y, mmL);
    kFused3<<<250, 256, 0, stream>>>(Y, out);
}

// Round 12
// 87.962 us; speedup vs baseline: 1.0537x; 1.0124x over previous
//
#include <hip/hip_runtime.h>
#include <math.h>

#define NS 256000
#define N1 512            // FFT over n1: radix 8,8,8
#define N2 500            // FFT over n2: radices 5,5,5,4
#define PI_F 3.14159265358979323846f

typedef float2 cplx;

__device__ __forceinline__ cplx cadd(cplx a, cplx b){ return make_float2(a.x+b.x, a.y+b.y); }
__device__ __forceinline__ cplx csub(cplx a, cplx b){ return make_float2(a.x-b.x, a.y-b.y); }
__device__ __forceinline__ cplx cmul(cplx a, cplx b){ return make_float2(a.x*b.x-a.y*b.y, a.x*b.y+a.y*b.x); }
__device__ __forceinline__ cplx cmulc(cplx a, cplx b){ return make_float2(a.x*b.x+a.y*b.y, a.y*b.x-a.x*b.y); }
__device__ __forceinline__ cplx crotf(cplx v, float ang){
    float sn = __sinf(ang), cs = __cosf(ang);
    return make_float2(v.x*cs - v.y*sn, v.x*sn + v.y*cs);
}
// padded LDS index: +1 word every 16 elements -> <=2-way bank aliasing
__device__ __forceinline__ int PX(int e){ return e + (e>>4); }
// octal digit reversal of 9 bits (involution)
__device__ __forceinline__ int rev8_3(int k){ return ((k&7)<<6) | (k&0x38) | (k>>6); }

#define U1PAD 545   // >= PX(511)+1 = 543
#define U2PAD 537   // >= PX(499)+1 = 531
// wave-level LDS fence: wave-private columns, no block barrier needed
#define WFENCE() asm volatile("s_waitcnt lgkmcnt(0)" ::: "memory")
// LDS-only block barrier: does NOT drain vmcnt, so global loads stay in flight
#define LDS_BARRIER() do{ asm volatile("s_waitcnt lgkmcnt(0)" ::: "memory"); __builtin_amdgcn_s_barrier(); }while(0)

template<bool INV>
__device__ __forceinline__ void dft4(const cplx* a, cplx* b){
    cplx t0=cadd(a[0],a[2]), t1=csub(a[0],a[2]), t2=cadd(a[1],a[3]), t3=csub(a[1],a[3]);
    b[0]=cadd(t0,t2); b[2]=csub(t0,t2);
    if(!INV){ b[1]=make_float2(t1.x+t3.y, t1.y-t3.x); b[3]=make_float2(t1.x-t3.y, t1.y+t3.x); }
    else    { b[1]=make_float2(t1.x-t3.y, t1.y+t3.x); b[3]=make_float2(t1.x+t3.y, t1.y-t3.x); }
}

template<bool INV>
__device__ __forceinline__ void dft8(const cplx* a, cplx* b){
    cplx ev[4]={a[0],a[2],a[4],a[6]}, od[4]={a[1],a[3],a[5],a[7]};
    cplx C[4], D[4];
    dft4<INV>(ev, C); dft4<INV>(od, D);
    const float s = 0.70710678118654752f;
    const float sg = INV ? 1.f : -1.f;
    cplx d1 = cmul(D[1], make_float2( s, sg*s));
    cplx d2 = cmul(D[2], make_float2(0.f, sg ));
    cplx d3 = cmul(D[3], make_float2(-s, sg*s));
    b[0]=cadd(C[0],D[0]); b[4]=csub(C[0],D[0]);
    b[1]=cadd(C[1],d1);   b[5]=csub(C[1],d1);
    b[2]=cadd(C[2],d2);   b[6]=csub(C[2],d2);
    b[3]=cadd(C[3],d3);   b[7]=csub(C[3],d3);
}

template<bool INV>
__device__ __forceinline__ void dft5(const cplx* a, cplx* b){
    const float c1=0.30901699437494742f, s1=0.95105651629515357f;
    const float c2=-0.80901699437494745f, s2=0.58778525229247312f;
    const float sg = INV ? 1.f : -1.f;
    cplx W[5];
    W[0]=make_float2(1.f,0.f);
    W[1]=make_float2(c1, sg*s1); W[2]=make_float2(c2, sg*s2);
    W[3]=make_float2(c2,-sg*s2); W[4]=make_float2(c1,-sg*s1);
#pragma unroll
    for(int u=0;u<5;++u){
        cplx acc = a[0];
        int idx = 0;
#pragma unroll
        for(int r=1;r<5;++r){
            idx += u; if(idx >= 5) idx -= 5;
            acc = cadd(acc, cmul(a[r], W[idx]));
        }
        b[u] = acc;
    }
}

// wave-private in-place stage: all reads issued first, then compute+write.
template<int R, int L, int TMUL, bool INV, int NN>
__device__ __forceinline__ void wstage(cplx* Uw, const cplx* tab, int lane){
    constexpr int m = L / R;
    constexpr int nb = NN / R;
    constexpr int NIT = (nb + 63) / 64;
    cplx a[NIT][R];
    cplx wt[NIT][R];   // wt[][0] unused
    int  bs[NIT];
#pragma unroll
    for(int it=0; it<NIT; ++it){
        int beta = lane + it*64;
        int blk = beta / m;
        int j = beta - blk*m;
        bs[it] = blk*L + j;
        if(beta < nb){
#pragma unroll
            for(int t=0;t<R;++t) a[it][t] = Uw[PX(bs[it] + m*t)];
#pragma unroll
            for(int t=1;t<R;++t) wt[it][t] = tab[TMUL*j*t];
        }
    }
#pragma unroll
    for(int it=0; it<NIT; ++it){
        int beta = lane + it*64;
        if(beta < nb){
            if(INV){
#pragma unroll
                for(int t=1;t<R;++t) a[it][t] = cmulc(a[it][t], wt[it][t]);
            }
            cplx bb[R];
            if constexpr (R==4) dft4<INV>(a[it], bb);
            else if constexpr (R==5) dft5<INV>(a[it], bb);
            else dft8<INV>(a[it], bb);
            if(!INV){
#pragma unroll
                for(int t=1;t<R;++t) bb[t] = cmul(bb[t], wt[it][t]);
            }
#pragma unroll
            for(int t=0;t<R;++t) Uw[PX(bs[it] + m*t)] = bb[t];
        }
    }
}

template<int NTAB, int NTHR>
__device__ __forceinline__ void build_tab(cplx* tab, int tid){
    const float step = -2.f*PI_F/(float)NTAB;
    for(int i = tid; i < NTAB; i += NTHR){
        float a = step*(float)i;
        tab[i] = make_float2(__cosf(a), __sinf(a));
    }
}

// position p -> true k2 for the radix-(5,5,5,4) DIF order
__device__ __forceinline__ int p2k2(int p){
    int t1 = p/100; int r = p - 100*t1;
    int t2 = r/20;  r -= 20*t2;
    int t3 = r>>2;  int t4 = r & 3;
    return t1 + 5*t2 + 25*t3 + 125*t4;
}
// true k2 -> position p (inverse of p2k2)
__device__ __forceinline__ int k22p(int k){
    int t1 = k % 5; int k5 = k/5;
    int t2 = k5 % 5; int k25 = k5/5;
    int t3 = k25 % 5; int t4 = k25/5;
    return 100*t1 + 20*t2 + 4*t3 + t4;
}
// slot -> true k1.  Conjugate pairs (k1, 512-k1) in adjacent slots:
// slot 0,1 = {0, 256} (self-paired), slot 2j,2j+1 = {j, 512-j} for j>=1.
__device__ __forceinline__ int colord(int q){
    int j = q>>1, w = q&1;
    if(j == 0) return w ? 256 : 0;
    return w ? 512 - j : j;
}
// bijective XCD-chunk swizzle
__device__ __forceinline__ int xcd_chunk(int bid, int n){
    int q = n>>3, r = n&7;
    int x = bid&7, idx = bid>>3;
    return (x < r ? x*(q+1) : r*(q+1) + (x-r)*q) + idx;
}

// packed conjugate-pair filter
__device__ __forceinline__ void hpair(cplx Z1, cplx Z2, float ha, float hb,
                                      cplx* zk, cplx* znk){
    float xr = 0.5f*(Z1.x + Z2.x), xi = 0.5f*(Z1.y - Z2.y);   // Xa
    float yr = 0.5f*(Z1.y + Z2.y), yi = -0.5f*(Z1.x - Z2.x);  // Xb
    *zk  = make_float2(ha*xr - hb*yi, ha*xi + hb*yr);
    *znk = make_float2(ha*xr + hb*yi, hb*yr - ha*xi);
}

// ---------------------------------------------------------------------------
// K1: blocks 0..3 = frame-mean weights (8-way ILP fm reduction); block 4 =
// logff; blocks 5.. = packed forward 512-FFT, 4 n2-columns per 4-wave block.
// ---------------------------------------------------------------------------
__global__ void __launch_bounds__(256) kFused1(const float* __restrict__ fm,
                                               const float* __restrict__ noise,
                                               float* __restrict__ mmL,
                                               cplx* __restrict__ Y){
    __shared__ float Aarr[500];
    __shared__ float wfr[500];
    __shared__ float part[256];
    __shared__ cplx tab[512];
    __shared__ cplx U[4][U1PAD];
    const int bid = blockIdx.x, tid = threadIdx.x;
    if(bid < 4){
        const int b = bid;
        for(int f = tid; f < 500; f += 256){
            long long i0 = ((long long)f*255999LL + 498LL)/499LL;
            long long i1 = ((long long)(f+1)*255999LL + 498LL)/499LL;
            long long cnt = i1 - i0;
            long long sumi = (i0 + i1 - 1)*cnt/2;
            long long num = 499LL*sumi - cnt*(long long)f*255999LL;
            Aarr[f] = (float)((double)num / 255999.0);
        }
        __syncthreads();
        for(int f = tid; f < 500; f += 256){
            long long i0 = ((long long)f*255999LL + 498LL)/499LL;
            long long i1 = ((long long)(f+1)*255999LL + 498LL)/499LL;
            double w;
            if(f < 499) w = (double)(i1 - i0) - (double)Aarr[f] + (f > 0 ? (double)Aarr[f-1] : 0.0);
            else        w = (double)Aarr[498] + 1.0;
            wfr[f] = (float)(w / (double)NS);
        }
        __syncthreads();
        // fm reduction with 8 independent accumulators -> 8 loads in flight
        const int k = tid & 63, seg = tid >> 6;
        const int f0 = seg*125;
        float ac[8];
#pragma unroll
        for(int u=0;u<8;++u) ac[u] = 0.f;
#pragma unroll 1
        for(int f = 0; f < 120; f += 8){
#pragma unroll
            for(int u=0;u<8;++u)
                ac[u] += wfr[f0+f+u] * fm[(b*500 + f0+f+u)*64 + k];
        }
#pragma unroll
        for(int u=0;u<5;++u)
            ac[u] += wfr[f0+120+u] * fm[(b*500 + f0+120+u)*64 + k];
        float acc = ((ac[0]+ac[1]) + (ac[2]+ac[3])) + ((ac[4]+ac[5]) + (ac[6]+ac[7]));
        part[seg*64 + k] = acc;
        __syncthreads();
        if(tid < 64) mmL[b*64 + tid] = part[tid] + part[64+tid] + part[128+tid] + part[192+tid];
        return;
    }
    if(bid == 4){
        if(tid < 64){
            float ff = __expf(2.99573227f + (float)tid*(6.31218815f/63.f));  // 20*551.25^(t/63)
            mmL[256 + tid] = __logf(ff + 1e-7f);
        }
        return;
    }
    // ---- packed forward 512-FFT: 4 columns per block ----
    const int g = xcd_chunk(bid - 5, 250);     // [0,250)
    const int s = g / 125;                     // signal
    const int n2base = (g - s*125) * 4;
    const int lane = tid & 63, w = tid >> 6;
    build_tab<512,256>(tab, tid);
    const float* xa = noise + (size_t)(2*s)*NS + n2base;
    const float* xb = noise + (size_t)(2*s+1)*NS + n2base;
#pragma unroll
    for(int k=0;k<8;++k){
        int i = tid + 256*k;                   // [0,2048)
        int n1 = i >> 2, ws = i & 3;
        U[ws][PX(n1)] = make_float2(xa[n1*500 + ws], xb[n1*500 + ws]);
    }
    __syncthreads();
    cplx* Uw = U[w];
    wstage<8,512, 1,false,512>(Uw, tab, lane); WFENCE();
    wstage<8, 64, 8,false,512>(Uw, tab, lane); WFENCE();
    wstage<8,  8,64,false,512>(Uw, tab, lane); WFENCE();
    const int n2 = n2base + w;
    cplx* yp = Y + ((size_t)s*500 + n2)*N1;
    const float tw = -2.f*PI_F/(float)NS;
#pragma unroll
    for(int t=0;t<8;++t){
        int q = lane + 64*t;
        int c = colord(q);
        cplx v = Uw[PX(rev8_3(c))];
        v = crotf(v, tw*(float)(n2*c));
        yp[q] = v;
    }
}

// ---------------------------------------------------------------------------
// K2: 256 blocks x 256 thr — ONE block-round on 256 CUs.  Each block owns 2
// conjugate pairs (4 columns); each wave owns one FULL 500-pt column
// (wave-private stages, no inter-stage block barriers).  Fused filter
// response; conjugate unpack -> filter -> repack between fwd/inv FFTs.
// In-place on Y.
// ---------------------------------------------------------------------------
__global__ void __launch_bounds__(256) kFused2(cplx* __restrict__ Y,
                                               const float* __restrict__ mmL){
    __shared__ cplx tab[500];
    __shared__ cplx U[4][U2PAD];
    __shared__ float Hr[2][2][500];   // [pair-unit][a0/a1][p]
    __shared__ float HrX[2][500];     // k1=256 rows (special block only)
    __shared__ float mmS[2][64];
    __shared__ float lgf[64];
    const int tid = threadIdx.x, lane = tid & 63, w = tid >> 6;
    const int L = xcd_chunk(blockIdx.x, 256);
    const int su = L >> 7;
    const int j0 = 2*(L & 127);           // first pair index (even)
    const int s0 = 2*j0;                  // first slot in Y
    cplx* Ybase = Y + (size_t)su*500*512 + s0;
    // issue the 4-column loads FIRST; in flight through tab/Hr compute
    cplx rg[8];
#pragma unroll
    for(int k=0;k<8;++k){
        int e = tid + 256*k;              // [0,2048) -> 2000 used
        rg[k] = (e < 2000) ? Ybase[(e>>2)*512 + (e&3)] : make_float2(0.f,0.f);
    }
    build_tab<500,256>(tab, tid);
    if(tid < 128) mmS[tid>>6][tid&63] = mmL[2*su*64 + tid];
    if(tid < 64)  lgf[tid] = mmL[256 + tid];
    LDS_BARRIER();                        // LDS visible; vmem NOT drained
    // filter response rows: r0 -> k1=j0, r1 -> j0+1, r2 -> 256 (special)
    const int special = (j0 == 0);
    const int nrows = special ? 3 : 2;
    const float invN = 1.f/(float)NS;
    for(int idx = tid; idx < nrows*500; idx += 256){
        int r = idx / 500;
        int p = idx - 500*r;
        int k1 = (r==0) ? j0 : ((r==1) ? j0+1 : 256);
        int k2 = p2k2(p);
        int kf = k1 + 512*k2;
        int kk = min(kf, NS - kf);
        float lf = __logf((float)kk*(22050.f/(float)NS) + 1e-7f);
        float wsum = 0.f, a0 = 0.f, a1 = 0.f;
#pragma unroll
        for(int jb=0;jb<64;++jb){
            float d = lf - lgf[jb];
            float e2 = __expf(-2.f*d*d);
            wsum += e2; a0 += e2*mmS[0][jb]; a1 += e2*mmS[1][jb];
        }
        float inv = invN/(wsum + 1e-7f);
        if(r < 2){ Hr[r][0][p] = a0*inv; Hr[r][1][p] = a1*inv; }
        else     { HrX[0][p]   = a0*inv; HrX[1][p]   = a1*inv; }
    }
    // park loads into LDS (compiler inserts the vmcnt waits here)
#pragma unroll
    for(int k=0;k<8;++k){
        int e = tid + 256*k;
        if(e < 2000) U[e&3][PX(e>>2)] = rg[k];
    }
    __syncthreads();
    cplx* Uw = U[w];
    wstage<5,500,  1,false,500>(Uw, tab, lane); WFENCE();
    wstage<5,100,  5,false,500>(Uw, tab, lane); WFENCE();
    wstage<5, 20, 25,false,500>(Uw, tab, lane); WFENCE();
    wstage<4,  4,125,false,500>(Uw, tab, lane);
    __syncthreads();
    // ---- conjugate-pair unpack -> filter -> repack ----
    {
        const int u = w >> 1, cw = w & 1;
        cplx* UA = U[2*u];
        cplx* UB = U[2*u + 1];
        if(special && u == 0){
            if(cw == 0){
                // column k1=0, self-paired: partner k2' = (500-k2)%500
#pragma unroll 1
                for(int t=0;t<8;++t){
                    int p = lane + 64*t;
                    if(p < 500){
                        int k2 = p2k2(p);
                        int pp = k22p((500 - k2) % 500);
                        if(p <= pp){
                            cplx Z1 = UA[PX(p)], Z2 = UA[PX(pp)];
                            cplx zk, znk;
                            hpair(Z1, Z2, Hr[0][0][p], Hr[0][1][p], &zk, &znk);
                            UA[PX(p)]  = zk;
                            UA[PX(pp)] = znk;
                        }
                    }
                }
            } else {
                // column k1=256, self-paired: partner position 499-p
#pragma unroll 1
                for(int t=0;t<4;++t){
                    int p = lane + 64*t;
                    if(p < 250){
                        cplx Z1 = UB[PX(p)], Z2 = UB[PX(499-p)];
                        cplx zk, znk;
                        hpair(Z1, Z2, HrX[0][p], HrX[1][p], &zk, &znk);
                        UB[PX(p)]     = zk;
                        UB[PX(499-p)] = znk;
                    }
                }
            }
        } else {
            // cross pair j=j0+u: (col k1=j, p) <-> (col 512-j, 499-p);
            // wave cw owns p in [cw*250, cw*250+250) -> disjoint writes.
            const float* H0 = Hr[u][0];
            const float* H1 = Hr[u][1];
#pragma unroll 1
            for(int t=0;t<4;++t){
                int pl = lane + 64*t;
                if(pl < 250){
                    int p = cw*250 + pl;
                    cplx Z1 = UA[PX(p)], Z2 = UB[PX(499-p)];
                    cplx zk, znk;
                    hpair(Z1, Z2, H0[p], H1[p], &zk, &znk);
                    UA[PX(p)]     = zk;
                    UB[PX(499-p)] = znk;
                }
            }
        }
    }
    __syncthreads();
    wstage<4,  4,125,true,500>(Uw, tab, lane); WFENCE();
    wstage<5, 20, 25,true,500>(Uw, tab, lane); WFENCE();
    wstage<5,100,  5,true,500>(Uw, tab, lane); WFENCE();
    wstage<5,500,  1,true,500>(Uw, tab, lane);
    __syncthreads();                      // store reads across all 4 columns
    const float tw2 = 2.f*PI_F/(float)NS;
#pragma unroll
    for(int k=0;k<8;++k){
        int e = tid + 256*k;
        if(e < 2000){
            int n2 = e >> 2, sl = e & 3;
            int cc = colord(s0 + sl);
            cplx v = U[sl][PX(n2)];
            v = crotf(v, tw2*(float)(n2*cc));
            Ybase[n2*512 + sl] = v;
        }
    }
}

// ---------------------------------------------------------------------------
// K3: inverse 512-FFT; 4 n2-columns per 4-wave block (wave-per-column).
// Re -> batch 2s, Im -> batch 2s+1.  grid = 250.
// ---------------------------------------------------------------------------
__global__ void __launch_bounds__(256) kFused3(const cplx* __restrict__ Y,
                                               float* __restrict__ out){
    __shared__ cplx tab[512];
    __shared__ cplx U[4][U1PAD];
    const int tid = threadIdx.x, lane = tid & 63, w = tid >> 6;
    const int g = xcd_chunk(blockIdx.x, 250);
    const int s = g / 125;
    const int n2base = (g - s*125) * 4;
    build_tab<512,256>(tab, tid);
    const cplx* yp = Y + ((size_t)s*500 + n2base)*N1;
#pragma unroll
    for(int k=0;k<8;++k){
        int i = tid + 256*k;                   // [0,2048)
        int ws = i >> 9, q = i & 511;          // coalesced in q
        cplx v = yp[(size_t)ws*N1 + q];
        U[ws][PX(rev8_3(colord(q)))] = v;      // bin c -> DIT position rev8_3(c)
    }
    __syncthreads();
    cplx* Uw = U[w];
    wstage<8,  8,64,true,512>(Uw, tab, lane); WFENCE();
    wstage<8, 64, 8,true,512>(Uw, tab, lane); WFENCE();
    wstage<8,512, 1,true,512>(Uw, tab, lane);
    __syncthreads();                           // store reads across columns
    float* oa = out + (size_t)(2*s)*NS + n2base;
    float* ob = out + (size_t)(2*s+1)*NS + n2base;
#pragma unroll
    for(int k=0;k<8;++k){
        int i = tid + 256*k;
        int n1 = i >> 2, ws = i & 3;
        cplx v = U[ws][PX(n1)];
        oa[n1*500 + ws] = v.x;
        ob[n1*500 + ws] = v.y;
    }
}

// ---------------------------------------------------------------------------
extern "C" void kernel_launch(void* const* d_in, const int* in_sizes, int n_in,
                              void* d_out, int out_size, void* d_ws, size_t ws_size,
                              hipStream_t stream) {
    const float* fm = (const float*)d_in[0];     // (4,500,64)
    const float* noise = (const float*)d_in[1];  // (4,256000)
    float* out = (float*)d_out;

    char* ws = (char*)d_ws;
    cplx*  Y   = (cplx*)ws;                      // 2 signals * 500 * 512 cplx = 4,096,000 B
    float* mmL = (float*)(ws + 4194304);         // mm[4][64] + logff[64]

    kFused1<<<255, 256, 0, stream>>>(fm, noise, mmL, Y);
    kFused2<<<256, 256, 0, stream>>>(Y, mmL);
    kFused3<<<250, 256, 0, stream>>>(Y, out);
}